// Round 1
// 508.026 us; speedup vs baseline: 1.0638x; 1.0638x over previous
//
#include <hip/hip_runtime.h>

#define NODES 100000
#define EDGES 1600000
#define FEATS 128
#define NCLS  16

// bucket = 64 consecutive dst nodes
#define BSH    6
#define BNODES 64
#define NB     ((NODES + BNODES - 1) / BNODES)   // 1563
#define CHUNK  8192
#define NBLK   ((EDGES + CHUNK - 1) / CHUNK)     // 196
#define NHIST  (NB * NBLK)                       // 306348
#define BCAP   2048                              // per-bucket LDS sort capacity

typedef unsigned int  u32;
typedef unsigned short u16;
typedef __attribute__((ext_vector_type(8))) short short8;
typedef __attribute__((ext_vector_type(4))) float f32x4;

__device__ __forceinline__ float b2f(u16 v){ return __uint_as_float(((u32)v)<<16); }
__device__ __forceinline__ u16 f2b(float f){
  u32 u = __float_as_uint(f);
  u += 0x7fffu + ((u>>16)&1u);   // RNE
  return (u16)(u>>16);
}
__device__ __forceinline__ float blo(u32 p){ return __uint_as_float(p<<16); }
__device__ __forceinline__ float bhi(u32 p){ return __uint_as_float(p & 0xffff0000u); }
__device__ __forceinline__ u32 pk2(float lo, float hi){
  return (u32)f2b(lo) | ((u32)f2b(hi) << 16);
}

// ---------------- phase A: per-chunk bucket histogram ----------------

__global__ __launch_bounds__(256) void pA_k(const int* __restrict__ dst,
                                            int* __restrict__ gh, int E){
  __shared__ int hist[NB];
  int t = threadIdx.x, blk = blockIdx.x;
  for (int j = t; j < NB; j += 256) hist[j] = 0;
  __syncthreads();
  int e0 = blk*CHUNK, e1 = e0 + CHUNK; if (e1 > E) e1 = E;
  for (int e = e0 + t; e < e1; e += 256) atomicAdd(&hist[dst[e] >> BSH], 1);
  __syncthreads();
  for (int j = t; j < NB; j += 256) gh[j*NBLK + blk] = hist[j];
}

// ---------------- phase B: exclusive scan of gh ----------------

__global__ __launch_bounds__(256) void scan1_k(const int* __restrict__ in, int* __restrict__ out,
                                               int* __restrict__ bsum, int n){
  __shared__ int sh[256];
  int t = threadIdx.x;
  int base = blockIdx.x*2048 + t*8;
  int v[8]; int s = 0;
  #pragma unroll
  for (int j=0;j<8;++j) v[j] = (base+j < n) ? in[base+j] : 0;
  #pragma unroll
  for (int j=0;j<8;++j){ int tmp = v[j]; v[j] = s; s += tmp; }
  sh[t] = s; __syncthreads();
  for (int off=1; off<256; off<<=1){
    int x = (t>=off) ? sh[t-off] : 0;
    __syncthreads();
    sh[t] += x;
    __syncthreads();
  }
  int excl = sh[t] - s;
  #pragma unroll
  for (int j=0;j<8;++j) if (base+j < n) out[base+j] = excl + v[j];
  if (t == 255) bsum[blockIdx.x] = sh[255];
}

// 256-entry block scan (nb <= 256)
__global__ __launch_bounds__(256) void scan2_k(const int* __restrict__ bsum,
                                               int* __restrict__ boff, int nb){
  __shared__ int sh[256];
  int t = threadIdx.x;
  int v = (t < nb) ? bsum[t] : 0;
  sh[t] = v; __syncthreads();
  for (int off=1; off<256; off<<=1){
    int x = (t>=off) ? sh[t-off] : 0;
    __syncthreads();
    sh[t] += x;
    __syncthreads();
  }
  if (t < nb) boff[t] = sh[t] - v;
}

__global__ void scan3_k(int* __restrict__ gscan, const int* __restrict__ boff,
                        int* __restrict__ bstart, int n){
  int i = blockIdx.x*256 + threadIdx.x;
  if (i < n){
    int v = gscan[i] + boff[i>>11];
    gscan[i] = v;
    if (i % NBLK == 0) bstart[i / NBLK] = v;
    if (i == 0) bstart[NB] = EDGES;
  }
}

// ---------------- phase C: LDS counting sort, then streamed coalesced write ----------------
// packed word: (dst & 63) << 17 | src

__global__ __launch_bounds__(256) void pC_k(const int* __restrict__ src,
    const int* __restrict__ dst, const int* __restrict__ gscan,
    u32* __restrict__ elist, int E){
  __shared__ int A[NB];        // hist -> excl -> delta
  __shared__ int B[NB];        // running local position (starts at excl)
  __shared__ int sp[256];      // scan partials
  __shared__ u32 pay[CHUNK];   // payload by local sorted index
  __shared__ u16 bkt[CHUNK];   // bucket by local sorted index
  int t = threadIdx.x, blk = blockIdx.x;
  for (int j = t; j < NB; j += 256) A[j] = 0;
  __syncthreads();
  int e0 = blk*CHUNK, e1 = e0 + CHUNK; if (e1 > E) e1 = E;
  int cnt = e1 - e0;
  for (int e = e0 + t; e < e1; e += 256) atomicAdd(&A[dst[e] >> BSH], 1);
  __syncthreads();
  // block-exclusive scan over A[0..NB): 7 elems/thread
  {
    int base = t*7;
    int cv[7]; int s = 0;
    #pragma unroll
    for (int j=0;j<7;++j){ int idx = base+j; cv[j] = (idx < NB) ? A[idx] : 0; s += cv[j]; }
    sp[t] = s; __syncthreads();
    for (int off=1; off<256; off<<=1){
      int x = (t>=off) ? sp[t-off] : 0;
      __syncthreads();
      sp[t] += x;
      __syncthreads();
    }
    int run = sp[t] - s;
    #pragma unroll
    for (int j=0;j<7;++j){
      int idx = base+j;
      if (idx < NB){ A[idx] = run; B[idx] = run; run += cv[j]; }
    }
  }
  __syncthreads();
  // delta[b] = global run start - local excl
  for (int j = t; j < NB; j += 256) A[j] = gscan[j*NBLK + blk] - A[j];
  __syncthreads();
  // placement into LDS sorted order
  for (int e = e0 + t; e < e1; e += 256){
    int d = dst[e];
    int b = d >> BSH;
    u32 w = ((u32)(d & (BNODES-1)) << 17) | (u32)src[e];
    int r = atomicAdd(&B[b], 1);
    pay[r] = w; bkt[r] = (u16)b;
  }
  __syncthreads();
  // streamed write: consecutive i -> consecutive global slots within runs
  for (int i = t; i < cnt; i += 256){
    int b = bkt[i];
    elist[i + A[b]] = pay[i];
  }
}

// ---------------- per-bucket counting sort (in place) + degrees ----------------

__global__ __launch_bounds__(256) void csr_k(u32* __restrict__ elist,
    const int* __restrict__ bstart, int* __restrict__ offs, int* __restrict__ degs,
    float* __restrict__ invd, int M){
  __shared__ int hist[BNODES];
  __shared__ int pos[BNODES];
  __shared__ u32 buf[BCAP];
  __shared__ u32 buf2[BCAP];
  int b = blockIdx.x, t = threadIdx.x;
  if (t < BNODES) hist[t] = 0;
  __syncthreads();
  int s0 = bstart[b];
  int cnt = bstart[b+1] - s0; if (cnt > BCAP) cnt = BCAP;
  u32* el = elist + s0;
  for (int e = t; e < cnt; e += 256){
    u32 w = el[e];
    buf[e] = w;
    atomicAdd(&hist[w>>17], 1);
  }
  __syncthreads();
  if (t < BNODES){                      // single-wave exclusive scan
    int v = hist[t];
    int s = v;
    for (int off = 1; off < BNODES; off <<= 1){
      int x = __shfl_up(s, off);
      if (t >= off) s += x;
    }
    int excl = s - v;
    pos[t] = excl;
    int node = b*BNODES + t;
    if (node < M){
      offs[node] = s0 + excl;
      degs[node] = v;
      invd[node] = 1.f / fmaxf((float)v, 1.f);
    }
  }
  __syncthreads();
  for (int e = t; e < cnt; e += 256){
    u32 w = buf[e];
    int p = atomicAdd(&pos[w>>17], 1);
    buf2[p] = w & 0x1FFFFu;             // keep src only
  }
  __syncthreads();
  for (int e = t; e < cnt; e += 256) el[e] = buf2[e];   // coalesced write-back
}

// ---------------- dtype conversion ----------------

__global__ void convf_k(const float* __restrict__ in, u16* __restrict__ o, int n4){
  int i = blockIdx.x*256 + threadIdx.x;
  if (i < n4){
    float4 x = ((const float4*)in)[i];
    ushort4 r;
    r.x = f2b(x.x); r.y = f2b(x.y); r.z = f2b(x.z); r.w = f2b(x.w);
    ((ushort4*)o)[i] = r;
  }
}

// W[K][N] row-major -> Wt[N][K] bf16
__global__ void convw_k(const float* __restrict__ W, u16* __restrict__ Wt, int Kd, int Nd){
  int i = blockIdx.x*256 + threadIdx.x;
  if (i < Kd*Nd){
    int k = i / Nd, nn = i - k*Nd;
    Wt[nn*Kd + k] = f2b(W[i]);
  }
}

// ---------------- GEMM: y[M x N] = h[M x 128] * W  (Wt is [N][128] bf16) ----------------

template<int NT>
__global__ __launch_bounds__(256) void gemm_k(const u16* __restrict__ h,
                                              const u16* __restrict__ Wt,
                                              u16* __restrict__ y, int M){
  const int K = FEATS;
  const int N = NT*16;
  int lane = threadIdx.x & 63;
  int wave = threadIdx.x >> 6;
  int m    = lane & 15;
  int quad = lane >> 4;
  int row0 = (blockIdx.x*4 + wave)*16;
  if (row0 >= M) return;
  int rowA = row0 + m; if (rowA > M-1) rowA = M-1;
  const u16* pa = h + (size_t)rowA*K + quad*8;

  f32x4 acc[NT];
  #pragma unroll
  for (int j=0;j<NT;++j) acc[j] = (f32x4){0.f,0.f,0.f,0.f};

  #pragma unroll
  for (int kk=0; kk<K; kk+=32){
    short8 a = *(const short8*)(pa + kk);
    #pragma unroll
    for (int j=0;j<NT;++j){
      short8 b = *(const short8*)(Wt + (size_t)(j*16 + m)*K + kk + quad*8);
      acc[j] = __builtin_amdgcn_mfma_f32_16x16x32_bf16(a, b, acc[j], 0, 0, 0);
    }
  }

  #pragma unroll
  for (int j=0;j<NT;++j){
    #pragma unroll
    for (int r=0;r<4;++r){
      int row = row0 + quad*4 + r;                  // C/D: row = quad*4 + reg
      if (row < M) y[(size_t)row*N + j*16 + m] = f2b(acc[j][r]);  // col = lane&15
    }
  }
}

// ---------------- 128-feat aggregation (layers 0..2) ----------------
// one wave per node; uint4 gathers: 4 rows per load instruction.
// c = lane&15 covers feats 8c..8c+7 (16 B); g = lane>>4 selects edge-in-quad.
// Unroll 4 quads = 16 edges = 4 KB in flight per wave.
// Row-group partials combined via shfl_xor(16) + shfl_xor(32).

__global__ __launch_bounds__(256) void aggL2_k(const u16* __restrict__ y,
    const u32* __restrict__ el, const int* __restrict__ offs,
    const int* __restrict__ degs, const float* __restrict__ invd,
    const float* __restrict__ bias, const float* __restrict__ epsv, int ei,
    u16* __restrict__ hout, int M){
  int lane = threadIdx.x & 63;
  int v = blockIdx.x*4 + (threadIdx.x >> 6);
  if (v >= M) return;
  int g = lane >> 4;          // edge-in-quad 0..3
  int c = lane & 15;          // feats 8c..8c+7
  const uint4* y16 = (const uint4*)y;   // row stride = 16 uint4
  int start = offs[v], deg = degs[v];
  float a0=0.f,a1=0.f,a2=0.f,a3=0.f,a4=0.f,a5=0.f,a6=0.f,a7=0.f;
  for (int eb = 0; eb < deg; eb += 64){
    int nn = deg - eb; if (nn > 64) nn = 64;
    int my = (lane < nn) ? (int)el[start + eb + lane] : 0;
    int nq = nn >> 2;
    int q = 0;
    for (; q + 4 <= nq; q += 4){
      int s0 = __shfl(my, 4*q      + g);
      int s1 = __shfl(my, 4*q + 4  + g);
      int s2 = __shfl(my, 4*q + 8  + g);
      int s3 = __shfl(my, 4*q + 12 + g);
      uint4 p0 = y16[(size_t)s0*16 + c];
      uint4 p1 = y16[(size_t)s1*16 + c];
      uint4 p2 = y16[(size_t)s2*16 + c];
      uint4 p3 = y16[(size_t)s3*16 + c];
      a0 += blo(p0.x)+blo(p1.x)+blo(p2.x)+blo(p3.x);
      a1 += bhi(p0.x)+bhi(p1.x)+bhi(p2.x)+bhi(p3.x);
      a2 += blo(p0.y)+blo(p1.y)+blo(p2.y)+blo(p3.y);
      a3 += bhi(p0.y)+bhi(p1.y)+bhi(p2.y)+bhi(p3.y);
      a4 += blo(p0.z)+blo(p1.z)+blo(p2.z)+blo(p3.z);
      a5 += bhi(p0.z)+bhi(p1.z)+bhi(p2.z)+bhi(p3.z);
      a6 += blo(p0.w)+blo(p1.w)+blo(p2.w)+blo(p3.w);
      a7 += bhi(p0.w)+bhi(p1.w)+bhi(p2.w)+bhi(p3.w);
    }
    for (; q < nq; ++q){
      int s = __shfl(my, 4*q + g);
      uint4 p = y16[(size_t)s*16 + c];
      a0 += blo(p.x); a1 += bhi(p.x); a2 += blo(p.y); a3 += bhi(p.y);
      a4 += blo(p.z); a5 += bhi(p.z); a6 += blo(p.w); a7 += bhi(p.w);
    }
    int rem = nn & 3;
    if (rem){
      int idx = 4*nq + g;
      bool valid = idx < nn;
      int s = __shfl(my, valid ? idx : 0);
      uint4 p = y16[(size_t)s*16 + c];
      if (valid){
        a0 += blo(p.x); a1 += bhi(p.x); a2 += blo(p.y); a3 += bhi(p.y);
        a4 += blo(p.z); a5 += bhi(p.z); a6 += blo(p.w); a7 += bhi(p.w);
      }
    }
  }
  // combine 4 row-group partials
  a0 += __shfl_xor(a0,16); a1 += __shfl_xor(a1,16); a2 += __shfl_xor(a2,16); a3 += __shfl_xor(a3,16);
  a4 += __shfl_xor(a4,16); a5 += __shfl_xor(a5,16); a6 += __shfl_xor(a6,16); a7 += __shfl_xor(a7,16);
  a0 += __shfl_xor(a0,32); a1 += __shfl_xor(a1,32); a2 += __shfl_xor(a2,32); a3 += __shfl_xor(a3,32);
  a4 += __shfl_xor(a4,32); a5 += __shfl_xor(a5,32); a6 += __shfl_xor(a6,32); a7 += __shfl_xor(a7,32);

  uint4 pv = y16[(size_t)v*16 + c];
  float4 bi0 = ((const float4*)bias)[2*c];
  float4 bi1 = ((const float4*)bias)[2*c+1];
  float inv = invd[v], e1s = 1.f + epsv[ei];
  float o0 = fmaxf(e1s*blo(pv.x) + inv*a0 + bi0.x, 0.f);
  float o1 = fmaxf(e1s*bhi(pv.x) + inv*a1 + bi0.y, 0.f);
  float o2 = fmaxf(e1s*blo(pv.y) + inv*a2 + bi0.z, 0.f);
  float o3 = fmaxf(e1s*bhi(pv.y) + inv*a3 + bi0.w, 0.f);
  float o4 = fmaxf(e1s*blo(pv.z) + inv*a4 + bi1.x, 0.f);
  float o5 = fmaxf(e1s*bhi(pv.z) + inv*a5 + bi1.y, 0.f);
  float o6 = fmaxf(e1s*blo(pv.w) + inv*a6 + bi1.z, 0.f);
  float o7 = fmaxf(e1s*bhi(pv.w) + inv*a7 + bi1.w, 0.f);
  if (g == 0){
    uint4 r;
    r.x = pk2(o0,o1); r.y = pk2(o2,o3); r.z = pk2(o4,o5); r.w = pk2(o6,o7);
    ((uint4*)hout)[(size_t)v*16 + c] = r;
  }
}

// ---------------- final 16-feat aggregation, f32 out, no relu ----------------
// 8 edges in parallel (sub = lane>>3), u32 loads (2 feats per lane).

__global__ __launch_bounds__(256) void aggF2_k(const u16* __restrict__ y,
    const u32* __restrict__ el, const int* __restrict__ offs,
    const int* __restrict__ degs, const float* __restrict__ invd,
    const float* __restrict__ bias, const float* __restrict__ epsv,
    float* __restrict__ out, int M){
  int lane = threadIdx.x & 63;
  int v = blockIdx.x*4 + (threadIdx.x >> 6);
  if (v >= M) return;
  int sub = lane >> 3;        // edge slot 0..7
  int f2  = lane & 7;         // feats 2f2, 2f2+1
  const u32* y2 = (const u32*)y;   // row stride = 8 u32
  int start = offs[v], deg = degs[v];
  float acc0 = 0.f, acc1 = 0.f;
  for (int e = sub; e < deg; e += 8){
    u32 s = el[start + e];
    u32 p = y2[(size_t)s*8 + f2];
    acc0 += blo(p); acc1 += bhi(p);
  }
  acc0 += __shfl_xor(acc0, 8);  acc1 += __shfl_xor(acc1, 8);
  acc0 += __shfl_xor(acc0, 16); acc1 += __shfl_xor(acc1, 16);
  acc0 += __shfl_xor(acc0, 32); acc1 += __shfl_xor(acc1, 32);
  if (sub == 0){
    u32 pv = y2[(size_t)v*8 + f2];
    float2 bi = ((const float2*)bias)[f2];
    float e1s = 1.f + epsv[3];
    float inv = invd[v];
    out[(size_t)v*NCLS + 2*f2    ] = e1s*blo(pv) + inv*acc0 + bi.x;
    out[(size_t)v*NCLS + 2*f2 + 1] = e1s*bhi(pv) + inv*acc1 + bi.y;
  }
}

// ---------------- launch ----------------

extern "C" void kernel_launch(void* const* d_in, const int* in_sizes, int n_in,
                              void* d_out, int out_size, void* d_ws, size_t ws_size,
                              hipStream_t stream){
  const float* feats = (const float*)d_in[0];
  const int*   src   = (const int*)d_in[1];
  const int*   dst   = (const int*)d_in[2];
  const float* W0 = (const float*)d_in[3];  const float* b0 = (const float*)d_in[4];
  const float* W1 = (const float*)d_in[5];  const float* b1 = (const float*)d_in[6];
  const float* W2 = (const float*)d_in[7];  const float* b2 = (const float*)d_in[8];
  const float* W3 = (const float*)d_in[9];  const float* b3 = (const float*)d_in[10];
  const float* eps = (const float*)d_in[11];

  char* w = (char*)d_ws;
  auto alloc = [&](size_t bytes)->char*{
    char* p = w; w += (bytes + 255) & ~(size_t)255; return p;
  };
  int*  gh    = (int*)alloc(sizeof(int)*NHIST);
  int*  gscan = (int*)alloc(sizeof(int)*NHIST);
  int*  bsum  = (int*)alloc(sizeof(int)*256);
  int*  boff  = (int*)alloc(sizeof(int)*256);
  int*  bstart= (int*)alloc(sizeof(int)*(NB+1));
  int*  offs  = (int*)alloc(sizeof(int)*NODES);
  int*  degs  = (int*)alloc(sizeof(int)*NODES);
  float* invd = (float*)alloc(sizeof(float)*NODES);
  u32*  elist = (u32*)alloc(sizeof(u32)*EDGES);
  u16*  hb    = (u16*)alloc(sizeof(u16)*(size_t)NODES*FEATS);
  u16*  yb    = (u16*)alloc(sizeof(u16)*(size_t)NODES*FEATS);
  u16*  Wt0   = (u16*)alloc(sizeof(u16)*128*128);
  u16*  Wt1   = (u16*)alloc(sizeof(u16)*128*128);
  u16*  Wt2   = (u16*)alloc(sizeof(u16)*128*128);
  u16*  Wt3   = (u16*)alloc(sizeof(u16)*16*128);

  // ---- deterministic 3-phase partition -> dense bucketed elist ----
  pA_k<<<NBLK, 256, 0, stream>>>(dst, gh, EDGES);
  int snb = (NHIST + 2047)/2048;                 // 150 <= 256
  scan1_k<<<snb, 256, 0, stream>>>(gh, gscan, bsum, NHIST);
  scan2_k<<<1, 256, 0, stream>>>(bsum, boff, snb);
  scan3_k<<<(NHIST+255)/256, 256, 0, stream>>>(gscan, boff, bstart, NHIST);
  pC_k<<<NBLK, 256, 0, stream>>>(src, dst, gscan, elist, EDGES);
  csr_k<<<NB, 256, 0, stream>>>(elist, bstart, offs, degs, invd, NODES);

  // ---- convert inputs to bf16 ----
  convf_k<<<((NODES*FEATS/4)+255)/256, 256, 0, stream>>>(feats, hb, NODES*FEATS/4);
  convw_k<<<(128*128+255)/256, 256, 0, stream>>>(W0, Wt0, 128, 128);
  convw_k<<<(128*128+255)/256, 256, 0, stream>>>(W1, Wt1, 128, 128);
  convw_k<<<(128*128+255)/256, 256, 0, stream>>>(W2, Wt2, 128, 128);
  convw_k<<<(128*16 +255)/256, 256, 0, stream>>>(W3, Wt3, 128, 16);

  int gblocks = (NODES + 63)/64;
  int ablocks = (NODES + 3)/4;

  // layers 0..2: y = h@W ; h = relu((1+eps)y + mean_agg(y) + b)
  gemm_k<8><<<gblocks, 256, 0, stream>>>(hb, Wt0, yb, NODES);
  aggL2_k<<<ablocks, 256, 0, stream>>>(yb, elist, offs, degs, invd, b0, eps, 0, hb, NODES);
  gemm_k<8><<<gblocks, 256, 0, stream>>>(hb, Wt1, yb, NODES);
  aggL2_k<<<ablocks, 256, 0, stream>>>(yb, elist, offs, degs, invd, b1, eps, 1, hb, NODES);
  gemm_k<8><<<gblocks, 256, 0, stream>>>(hb, Wt2, yb, NODES);
  aggL2_k<<<ablocks, 256, 0, stream>>>(yb, elist, offs, degs, invd, b2, eps, 2, hb, NODES);

  // layer 3: y = h@W3 (N=16); out = (1+eps)y + mean_agg(y) + b  (f32, no relu)
  gemm_k<1><<<gblocks, 256, 0, stream>>>(hb, Wt3, yb, NODES);
  aggF2_k<<<ablocks, 256, 0, stream>>>(yb, elist, offs, degs, invd, b3, eps, (float*)d_out, NODES);
}

// Round 3
// 505.263 us; speedup vs baseline: 1.0696x; 1.0055x over previous
//
#include <hip/hip_runtime.h>

#define NODES 100000
#define EDGES 1600000
#define FEATS 128
#define NCLS  16

// bucket = 64 consecutive dst nodes
#define BSH    6
#define BNODES 64
#define NB     ((NODES + BNODES - 1) / BNODES)   // 1563
#define CHUNK  8192
#define NBLK   ((EDGES + CHUNK - 1) / CHUNK)     // 196
#define NHIST  (NB * NBLK)                       // 306348
#define BCAP   2048                              // per-bucket LDS sort capacity
#define NGRP   ((NODES + 15) / 16)               // 6250 groups of 16 dst nodes

typedef unsigned int  u32;
typedef unsigned short u16;
typedef unsigned long long u64;
typedef __attribute__((ext_vector_type(8))) short short8;
typedef __attribute__((ext_vector_type(4))) float f32x4;

__device__ __forceinline__ float b2f(u16 v){ return __uint_as_float(((u32)v)<<16); }
__device__ __forceinline__ u16 f2b(float f){
  u32 u = __float_as_uint(f);
  u += 0x7fffu + ((u>>16)&1u);   // RNE
  return (u16)(u>>16);
}
__device__ __forceinline__ float blo(u32 p){ return __uint_as_float(p<<16); }
__device__ __forceinline__ float bhi(u32 p){ return __uint_as_float(p & 0xffff0000u); }

// global(16B) -> LDS, linear dest (wave-uniform base + lane*16), per-lane global src
__device__ __forceinline__ void gload16(const u16* g, u16* l){
  __builtin_amdgcn_global_load_lds(
      (const __attribute__((address_space(1))) u32*)g,
      (__attribute__((address_space(3))) u32*)l, 16, 0, 0);
}

// ---------------- phase A: per-chunk bucket histogram ----------------

__global__ __launch_bounds__(256) void pA_k(const int* __restrict__ dst,
                                            int* __restrict__ gh, int E){
  __shared__ int hist[NB];
  int t = threadIdx.x, blk = blockIdx.x;
  for (int j = t; j < NB; j += 256) hist[j] = 0;
  __syncthreads();
  int e0 = blk*CHUNK, e1 = e0 + CHUNK; if (e1 > E) e1 = E;
  for (int e = e0 + t; e < e1; e += 256) atomicAdd(&hist[dst[e] >> BSH], 1);
  __syncthreads();
  for (int j = t; j < NB; j += 256) gh[j*NBLK + blk] = hist[j];
}

// ---------------- phase B: exclusive scan of gh ----------------

__global__ __launch_bounds__(256) void scan1_k(const int* __restrict__ in, int* __restrict__ out,
                                               int* __restrict__ bsum, int n){
  __shared__ int sh[256];
  int t = threadIdx.x;
  int base = blockIdx.x*2048 + t*8;
  int v[8]; int s = 0;
  #pragma unroll
  for (int j=0;j<8;++j) v[j] = (base+j < n) ? in[base+j] : 0;
  #pragma unroll
  for (int j=0;j<8;++j){ int tmp = v[j]; v[j] = s; s += tmp; }
  sh[t] = s; __syncthreads();
  for (int off=1; off<256; off<<=1){
    int x = (t>=off) ? sh[t-off] : 0;
    __syncthreads();
    sh[t] += x;
    __syncthreads();
  }
  int excl = sh[t] - s;
  #pragma unroll
  for (int j=0;j<8;++j) if (base+j < n) out[base+j] = excl + v[j];
  if (t == 255) bsum[blockIdx.x] = sh[255];
}

// 256-entry block scan (nb <= 256)
__global__ __launch_bounds__(256) void scan2_k(const int* __restrict__ bsum,
                                               int* __restrict__ boff, int nb){
  __shared__ int sh[256];
  int t = threadIdx.x;
  int v = (t < nb) ? bsum[t] : 0;
  sh[t] = v; __syncthreads();
  for (int off=1; off<256; off<<=1){
    int x = (t>=off) ? sh[t-off] : 0;
    __syncthreads();
    sh[t] += x;
    __syncthreads();
  }
  if (t < nb) boff[t] = sh[t] - v;
}

__global__ void scan3_k(int* __restrict__ gscan, const int* __restrict__ boff,
                        int* __restrict__ bstart, int n){
  int i = blockIdx.x*256 + threadIdx.x;
  if (i < n){
    int v = gscan[i] + boff[i>>11];
    gscan[i] = v;
    if (i % NBLK == 0) bstart[i / NBLK] = v;
    if (i == 0) bstart[NB] = EDGES;
  }
}

// ---------------- phase C: LDS counting sort, then streamed coalesced write ----------------
// packed word: (dst & 63) << 17 | src

__global__ __launch_bounds__(256) void pC_k(const int* __restrict__ src,
    const int* __restrict__ dst, const int* __restrict__ gscan,
    u32* __restrict__ elist, int E){
  __shared__ int A[NB];        // hist -> excl -> delta
  __shared__ int B[NB];        // running local position (starts at excl)
  __shared__ int sp[256];      // scan partials
  __shared__ u32 pay[CHUNK];   // payload by local sorted index
  __shared__ u16 bkt[CHUNK];   // bucket by local sorted index
  int t = threadIdx.x, blk = blockIdx.x;
  for (int j = t; j < NB; j += 256) A[j] = 0;
  __syncthreads();
  int e0 = blk*CHUNK, e1 = e0 + CHUNK; if (e1 > E) e1 = E;
  int cnt = e1 - e0;
  for (int e = e0 + t; e < e1; e += 256) atomicAdd(&A[dst[e] >> BSH], 1);
  __syncthreads();
  // block-exclusive scan over A[0..NB): 7 elems/thread
  {
    int base = t*7;
    int cv[7]; int s = 0;
    #pragma unroll
    for (int j=0;j<7;++j){ int idx = base+j; cv[j] = (idx < NB) ? A[idx] : 0; s += cv[j]; }
    sp[t] = s; __syncthreads();
    for (int off=1; off<256; off<<=1){
      int x = (t>=off) ? sp[t-off] : 0;
      __syncthreads();
      sp[t] += x;
      __syncthreads();
    }
    int run = sp[t] - s;
    #pragma unroll
    for (int j=0;j<7;++j){
      int idx = base+j;
      if (idx < NB){ A[idx] = run; B[idx] = run; run += cv[j]; }
    }
  }
  __syncthreads();
  // delta[b] = global run start - local excl
  for (int j = t; j < NB; j += 256) A[j] = gscan[j*NBLK + blk] - A[j];
  __syncthreads();
  // placement into LDS sorted order
  for (int e = e0 + t; e < e1; e += 256){
    int d = dst[e];
    int b = d >> BSH;
    u32 w = ((u32)(d & (BNODES-1)) << 17) | (u32)src[e];
    int r = atomicAdd(&B[b], 1);
    pay[r] = w; bkt[r] = (u16)b;
  }
  __syncthreads();
  // streamed write: consecutive i -> consecutive global slots within runs
  for (int i = t; i < cnt; i += 256){
    int b = bkt[i];
    elist[i + A[b]] = pay[i];
  }
}

// ---------------- per-bucket counting sort (in place) + degrees ----------------
// NOTE: keeps the full packed word (dstloc<<17 | src) in elist.

__global__ __launch_bounds__(256) void csr_k(u32* __restrict__ elist,
    const int* __restrict__ bstart, int* __restrict__ offs, int* __restrict__ degs,
    float* __restrict__ invd, int M){
  __shared__ int hist[BNODES];
  __shared__ int pos[BNODES];
  __shared__ u32 buf[BCAP];
  __shared__ u32 buf2[BCAP];
  int b = blockIdx.x, t = threadIdx.x;
  if (b == 0 && t == 0) offs[M] = EDGES;     // sentinel for group ranges
  if (t < BNODES) hist[t] = 0;
  __syncthreads();
  int s0 = bstart[b];
  int cnt = bstart[b+1] - s0; if (cnt > BCAP) cnt = BCAP;
  u32* el = elist + s0;
  for (int e = t; e < cnt; e += 256){
    u32 w = el[e];
    buf[e] = w;
    atomicAdd(&hist[w>>17], 1);
  }
  __syncthreads();
  if (t < BNODES){                      // single-wave exclusive scan
    int v = hist[t];
    int s = v;
    for (int off = 1; off < BNODES; off <<= 1){
      int x = __shfl_up(s, off);
      if (t >= off) s += x;
    }
    int excl = s - v;
    pos[t] = excl;
    int node = b*BNODES + t;
    if (node < M){
      offs[node] = s0 + excl;
      degs[node] = v;
      invd[node] = 1.f / fmaxf((float)v, 1.f);
    }
  }
  __syncthreads();
  for (int e = t; e < cnt; e += 256){
    u32 w = buf[e];
    int p = atomicAdd(&pos[w>>17], 1);
    buf2[p] = w;                        // keep dstloc bits for MFMA aggregation
  }
  __syncthreads();
  for (int e = t; e < cnt; e += 256) el[e] = buf2[e];   // coalesced write-back
}

// ---------------- dtype conversion ----------------

__global__ void convf_k(const float* __restrict__ in, u16* __restrict__ o, int n4){
  int i = blockIdx.x*256 + threadIdx.x;
  if (i < n4){
    float4 x = ((const float4*)in)[i];
    ushort4 r;
    r.x = f2b(x.x); r.y = f2b(x.y); r.z = f2b(x.z); r.w = f2b(x.w);
    ((ushort4*)o)[i] = r;
  }
}

// W[K][N] row-major -> Wt[N][K] bf16
__global__ void convw_k(const float* __restrict__ W, u16* __restrict__ Wt, int Kd, int Nd){
  int i = blockIdx.x*256 + threadIdx.x;
  if (i < Kd*Nd){
    int k = i / Nd, nn = i - k*Nd;
    Wt[nn*Kd + k] = f2b(W[i]);
  }
}

// ---------------- GEMM: y[M x N] = h[M x 128] * W  (Wt is [N][128] bf16) ----------------

template<int NT>
__global__ __launch_bounds__(256) void gemm_k(const u16* __restrict__ h,
                                              const u16* __restrict__ Wt,
                                              u16* __restrict__ y, int M){
  const int K = FEATS;
  const int N = NT*16;
  int lane = threadIdx.x & 63;
  int wave = threadIdx.x >> 6;
  int m    = lane & 15;
  int quad = lane >> 4;
  int row0 = (blockIdx.x*4 + wave)*16;
  if (row0 >= M) return;
  int rowA = row0 + m; if (rowA > M-1) rowA = M-1;
  const u16* pa = h + (size_t)rowA*K + quad*8;

  f32x4 acc[NT];
  #pragma unroll
  for (int j=0;j<NT;++j) acc[j] = (f32x4){0.f,0.f,0.f,0.f};

  #pragma unroll
  for (int kk=0; kk<K; kk+=32){
    short8 a = *(const short8*)(pa + kk);
    #pragma unroll
    for (int j=0;j<NT;++j){
      short8 b = *(const short8*)(Wt + (size_t)(j*16 + m)*K + kk + quad*8);
      acc[j] = __builtin_amdgcn_mfma_f32_16x16x32_bf16(a, b, acc[j], 0, 0, 0);
    }
  }

  #pragma unroll
  for (int j=0;j<NT;++j){
    #pragma unroll
    for (int r=0;r<4;++r){
      int row = row0 + quad*4 + r;                  // C/D: row = quad*4 + reg
      if (row < M) y[(size_t)row*N + j*16 + m] = f2b(acc[j][r]);  // col = lane&15
    }
  }
}

// ---------------- MFMA aggregation (layers 0..2) ----------------
// One wave per 16 dst nodes. Per 32-edge k-step:
//   - gather 32 neighbor rows (256B each) into LDS as 4x16 subtiles:
//     subtile (i,cg) at byte i*1024+cg*128 holds rows 4i..4i+3 x cols 16cg..16cg+15
//   - indicator A-fragment (A[m][k] = 1 if edge k's dst-local == m)
//   - B-fragments via ds_read_b64_tr_b16 with PER-LANE addr base+(lane&15)*8
//     (m156/m162: column = addr bits [6:3], region = 128B-aligned block;
//      uniform addr reads one value — lane offset must be in the address)
//   - 8 MFMAs accumulate 16x128 output
// Epilogue: exact f32  relu((1+eps)*y[v] + inv*sum + b), bf16 store.

#define TRRD(dstv, lit) asm volatile("ds_read_b64_tr_b16 %0, %1 offset:" lit \
                                     : "=v"(dstv) : "v"(trb2))

__global__ __launch_bounds__(256) void aggM_k(const u16* __restrict__ y,
    const u32* __restrict__ el, const int* __restrict__ offs,
    const float* __restrict__ invd, const float* __restrict__ bias,
    const float* __restrict__ epsv, int ei, u16* __restrict__ hout){
  __shared__ __align__(128) u16 ybuf[4][4096];   // 8 KB per wave, 128B-aligned
  int lane = threadIdx.x & 63;
  int wave = threadIdx.x >> 6;
  int grp = blockIdx.x*4 + wave;
  if (grp >= NGRP) return;
  int v0 = grp << 4;
  int m    = lane & 15;
  int quad = lane >> 4;
  u32 tgt = (u32)(((grp & 3) << 4) + m);   // this lane's A-row as dst&63 value

  u16* lb = &ybuf[wave][0];
  typedef __attribute__((address_space(3))) u16 lds_u16;
  u32 lbaddr = (u32)(size_t)(lds_u16*)lb;
  // tr-read base: subtile row-block quad*2 (bytes quad*2048), column slot m*8.
  // offset: immediates walk jh*1024 + cb*128.
  u32 trb2 = lbaddr + (u32)(quad*2048) + (u32)(m*8);

  // gather addressing: inst i, lane l fetches row 4i+((l&7)>>1),
  // u16 cols (l>>3)*16 + (l&1)*8 .. +8  -> lands at subtiled LDS slot l*16B
  int rsel = (lane & 7) >> 1;
  int gcol = ((lane >> 3) << 4) + ((lane & 1) << 3);

  int e0 = offs[v0];
  int e1 = offs[v0 + 16];
  int nstep = (e1 - e0 + 31) >> 5;

  f32x4 acc[8];
  #pragma unroll
  for (int cb=0;cb<8;++cb) acc[cb] = (f32x4){0.f,0.f,0.f,0.f};

  for (int st = 0; st < nstep; ++st){
    int idx = e0 + (st<<5) + (lane & 31);
    u32 w = (idx < e1) ? el[idx] : 0xFFFE0000u;   // pad: dstloc=0x7FFF, src=0

    #pragma unroll
    for (int i=0;i<8;++i){
      u32 ws = (u32)__shfl((int)w, 4*i + rsel);
      int srow = (int)(ws & 0x1FFFFu);
      gload16(y + ((size_t)srow << 7) + gcol, lb + i*512);
    }

    // indicator A-fragment: lane holds A[m][quad*8+j], j=0..7 (bf16 1.0/0.0)
    union { u32 wv[4]; short8 s; } au;
    #pragma unroll
    for (int p=0;p<4;++p){
      u32 w0 = (u32)__shfl((int)w, quad*8 + 2*p);
      u32 w1 = (u32)__shfl((int)w, quad*8 + 2*p + 1);
      au.wv[p] = (((w0>>17) == tgt) ? 0x3F80u : 0u)
               | (((w1>>17) == tgt) ? 0x3F800000u : 0u);
    }

    asm volatile("s_waitcnt vmcnt(0)" ::: "memory");
    __builtin_amdgcn_sched_barrier(0);

    u64 t[16];
    TRRD(t[0],  "0");    TRRD(t[1],  "1024");
    TRRD(t[2],  "128");  TRRD(t[3],  "1152");
    TRRD(t[4],  "256");  TRRD(t[5],  "1280");
    TRRD(t[6],  "384");  TRRD(t[7],  "1408");
    TRRD(t[8],  "512");  TRRD(t[9],  "1536");
    TRRD(t[10], "640");  TRRD(t[11], "1664");
    TRRD(t[12], "768");  TRRD(t[13], "1792");
    TRRD(t[14], "896");  TRRD(t[15], "1920");
    asm volatile("s_waitcnt lgkmcnt(0)" ::: "memory");
    __builtin_amdgcn_sched_barrier(0);

    #pragma unroll
    for (int cb=0;cb<8;++cb){
      union { u64 d[2]; short8 s; } bu;
      bu.d[0] = t[2*cb]; bu.d[1] = t[2*cb+1];
      acc[cb] = __builtin_amdgcn_mfma_f32_16x16x32_bf16(au.s, bu.s, acc[cb], 0, 0, 0);
    }
  }

  // epilogue: rows quad*4+r, cols cb*16+m
  float myinv = invd[v0 + m];
  float invr[4];
  #pragma unroll
  for (int r=0;r<4;++r) invr[r] = __shfl(myinv, quad*4 + r);
  float e1s = 1.f + epsv[ei];
  #pragma unroll
  for (int cb=0;cb<8;++cb){
    float bi = bias[cb*16 + m];
    #pragma unroll
    for (int r=0;r<4;++r){
      size_t off = (size_t)(v0 + quad*4 + r)*FEATS + cb*16 + m;
      float self = b2f(y[off]);
      float o = fmaxf(e1s*self + invr[r]*acc[cb][r] + bi, 0.f);
      hout[off] = f2b(o);
    }
  }
}

// ---------------- final 16-feat aggregation, f32 out, no relu ----------------
// 8 edges in parallel (sub = lane>>3), u32 loads (2 feats per lane).

__global__ __launch_bounds__(256) void aggF2_k(const u16* __restrict__ y,
    const u32* __restrict__ el, const int* __restrict__ offs,
    const int* __restrict__ degs, const float* __restrict__ invd,
    const float* __restrict__ bias, const float* __restrict__ epsv,
    float* __restrict__ out, int M){
  int lane = threadIdx.x & 63;
  int v = blockIdx.x*4 + (threadIdx.x >> 6);
  if (v >= M) return;
  int sub = lane >> 3;        // edge slot 0..7
  int f2  = lane & 7;         // feats 2f2, 2f2+1
  const u32* y2 = (const u32*)y;   // row stride = 8 u32
  int start = offs[v], deg = degs[v];
  float acc0 = 0.f, acc1 = 0.f;
  for (int e = sub; e < deg; e += 8){
    u32 s = el[start + e] & 0x1FFFFu;
    u32 p = y2[(size_t)s*8 + f2];
    acc0 += blo(p); acc1 += bhi(p);
  }
  acc0 += __shfl_xor(acc0, 8);  acc1 += __shfl_xor(acc1, 8);
  acc0 += __shfl_xor(acc0, 16); acc1 += __shfl_xor(acc1, 16);
  acc0 += __shfl_xor(acc0, 32); acc1 += __shfl_xor(acc1, 32);
  if (sub == 0){
    u32 pv = y2[(size_t)v*8 + f2];
    float2 bi = ((const float2*)bias)[f2];
    float e1s = 1.f + epsv[3];
    float inv = invd[v];
    out[(size_t)v*NCLS + 2*f2    ] = e1s*blo(pv) + inv*acc0 + bi.x;
    out[(size_t)v*NCLS + 2*f2 + 1] = e1s*bhi(pv) + inv*acc1 + bi.y;
  }
}

// ---------------- launch ----------------

extern "C" void kernel_launch(void* const* d_in, const int* in_sizes, int n_in,
                              void* d_out, int out_size, void* d_ws, size_t ws_size,
                              hipStream_t stream){
  const float* feats = (const float*)d_in[0];
  const int*   src   = (const int*)d_in[1];
  const int*   dst   = (const int*)d_in[2];
  const float* W0 = (const float*)d_in[3];  const float* b0 = (const float*)d_in[4];
  const float* W1 = (const float*)d_in[5];  const float* b1 = (const float*)d_in[6];
  const float* W2 = (const float*)d_in[7];  const float* b2 = (const float*)d_in[8];
  const float* W3 = (const float*)d_in[9];  const float* b3 = (const float*)d_in[10];
  const float* eps = (const float*)d_in[11];

  char* w = (char*)d_ws;
  auto alloc = [&](size_t bytes)->char*{
    char* p = w; w += (bytes + 255) & ~(size_t)255; return p;
  };
  int*  gh    = (int*)alloc(sizeof(int)*NHIST);
  int*  gscan = (int*)alloc(sizeof(int)*NHIST);
  int*  bsum  = (int*)alloc(sizeof(int)*256);
  int*  boff  = (int*)alloc(sizeof(int)*256);
  int*  bstart= (int*)alloc(sizeof(int)*(NB+1));
  int*  offs  = (int*)alloc(sizeof(int)*(NODES+1));
  int*  degs  = (int*)alloc(sizeof(int)*NODES);
  float* invd = (float*)alloc(sizeof(float)*NODES);
  u32*  elist = (u32*)alloc(sizeof(u32)*EDGES);
  u16*  hb    = (u16*)alloc(sizeof(u16)*(size_t)NODES*FEATS);
  u16*  yb    = (u16*)alloc(sizeof(u16)*(size_t)NODES*FEATS);
  u16*  Wt0   = (u16*)alloc(sizeof(u16)*128*128);
  u16*  Wt1   = (u16*)alloc(sizeof(u16)*128*128);
  u16*  Wt2   = (u16*)alloc(sizeof(u16)*128*128);
  u16*  Wt3   = (u16*)alloc(sizeof(u16)*16*128);

  // ---- deterministic 3-phase partition -> dense bucketed elist ----
  pA_k<<<NBLK, 256, 0, stream>>>(dst, gh, EDGES);
  int snb = (NHIST + 2047)/2048;                 // 150 <= 256
  scan1_k<<<snb, 256, 0, stream>>>(gh, gscan, bsum, NHIST);
  scan2_k<<<1, 256, 0, stream>>>(bsum, boff, snb);
  scan3_k<<<(NHIST+255)/256, 256, 0, stream>>>(gscan, boff, bstart, NHIST);
  pC_k<<<NBLK, 256, 0, stream>>>(src, dst, gscan, elist, EDGES);
  csr_k<<<NB, 256, 0, stream>>>(elist, bstart, offs, degs, invd, NODES);

  // ---- convert inputs to bf16 ----
  convf_k<<<((NODES*FEATS/4)+255)/256, 256, 0, stream>>>(feats, hb, NODES*FEATS/4);
  convw_k<<<(128*128+255)/256, 256, 0, stream>>>(W0, Wt0, 128, 128);
  convw_k<<<(128*128+255)/256, 256, 0, stream>>>(W1, Wt1, 128, 128);
  convw_k<<<(128*128+255)/256, 256, 0, stream>>>(W2, Wt2, 128, 128);
  convw_k<<<(128*16 +255)/256, 256, 0, stream>>>(W3, Wt3, 128, 16);

  int gblocks = (NODES + 63)/64;
  int mblocks = (NGRP + 3)/4;
  int ablocks = (NODES + 3)/4;

  // layers 0..2: y = h@W ; h = relu((1+eps)y + mean_agg(y) + b)
  gemm_k<8><<<gblocks, 256, 0, stream>>>(hb, Wt0, yb, NODES);
  aggM_k<<<mblocks, 256, 0, stream>>>(yb, elist, offs, invd, b0, eps, 0, hb);
  gemm_k<8><<<gblocks, 256, 0, stream>>>(hb, Wt1, yb, NODES);
  aggM_k<<<mblocks, 256, 0, stream>>>(yb, elist, offs, invd, b1, eps, 1, hb);
  gemm_k<8><<<gblocks, 256, 0, stream>>>(hb, Wt2, yb, NODES);
  aggM_k<<<mblocks, 256, 0, stream>>>(yb, elist, offs, invd, b2, eps, 2, hb);

  // layer 3: y = h@W3 (N=16); out = (1+eps)y + mean_agg(y) + b  (f32, no relu)
  gemm_k<1><<<gblocks, 256, 0, stream>>>(hb, Wt3, yb, NODES);
  aggF2_k<<<ablocks, 256, 0, stream>>>(yb, elist, offs, degs, invd, b3, eps, (float*)d_out, NODES);
}

// Round 4
// 499.158 us; speedup vs baseline: 1.0827x; 1.0122x over previous
//
#include <hip/hip_runtime.h>

#define NODES 100000
#define EDGES 1600000
#define FEATS 128
#define NCLS  16

// bucket = 64 consecutive dst nodes
#define BSH    6
#define BNODES 64
#define NB     ((NODES + BNODES - 1) / BNODES)   // 1563
#define CHUNK  8192
#define NBLK   ((EDGES + CHUNK - 1) / CHUNK)     // 196
#define NHIST  (NB * NBLK)                       // 306348
#define BCAP   2048                              // per-bucket LDS sort capacity
#define NGRP   ((NODES + 15) / 16)               // 6250 groups of 16 dst nodes

typedef unsigned int  u32;
typedef unsigned short u16;
typedef unsigned long long u64;
typedef __attribute__((ext_vector_type(8))) short short8;
typedef __attribute__((ext_vector_type(4))) float f32x4;

__device__ __forceinline__ float b2f(u16 v){ return __uint_as_float(((u32)v)<<16); }
__device__ __forceinline__ u16 f2b(float f){
  u32 u = __float_as_uint(f);
  u += 0x7fffu + ((u>>16)&1u);   // RNE
  return (u16)(u>>16);
}
__device__ __forceinline__ float blo(u32 p){ return __uint_as_float(p<<16); }
__device__ __forceinline__ float bhi(u32 p){ return __uint_as_float(p & 0xffff0000u); }

// global(16B) -> LDS, linear dest (wave-uniform base + lane*16), per-lane global src
__device__ __forceinline__ void gload16(const u16* g, u16* l){
  __builtin_amdgcn_global_load_lds(
      (const __attribute__((address_space(1))) u32*)g,
      (__attribute__((address_space(3))) u32*)l, 16, 0, 0);
}

// ---------------- phase A: per-chunk bucket histogram ----------------

__global__ __launch_bounds__(256) void pA_k(const int* __restrict__ dst,
                                            int* __restrict__ gh, int E){
  __shared__ int hist[NB];
  int t = threadIdx.x, blk = blockIdx.x;
  for (int j = t; j < NB; j += 256) hist[j] = 0;
  __syncthreads();
  int e0 = blk*CHUNK, e1 = e0 + CHUNK; if (e1 > E) e1 = E;
  for (int e = e0 + t; e < e1; e += 256) atomicAdd(&hist[dst[e] >> BSH], 1);
  __syncthreads();
  for (int j = t; j < NB; j += 256) gh[j*NBLK + blk] = hist[j];
}

// ---------------- phase B: exclusive scan of gh ----------------

__global__ __launch_bounds__(256) void scan1_k(const int* __restrict__ in, int* __restrict__ out,
                                               int* __restrict__ bsum, int n){
  __shared__ int sh[256];
  int t = threadIdx.x;
  int base = blockIdx.x*2048 + t*8;
  int v[8]; int s = 0;
  #pragma unroll
  for (int j=0;j<8;++j) v[j] = (base+j < n) ? in[base+j] : 0;
  #pragma unroll
  for (int j=0;j<8;++j){ int tmp = v[j]; v[j] = s; s += tmp; }
  sh[t] = s; __syncthreads();
  for (int off=1; off<256; off<<=1){
    int x = (t>=off) ? sh[t-off] : 0;
    __syncthreads();
    sh[t] += x;
    __syncthreads();
  }
  int excl = sh[t] - s;
  #pragma unroll
  for (int j=0;j<8;++j) if (base+j < n) out[base+j] = excl + v[j];
  if (t == 255) bsum[blockIdx.x] = sh[255];
}

// 256-entry block scan (nb <= 256)
__global__ __launch_bounds__(256) void scan2_k(const int* __restrict__ bsum,
                                               int* __restrict__ boff, int nb){
  __shared__ int sh[256];
  int t = threadIdx.x;
  int v = (t < nb) ? bsum[t] : 0;
  sh[t] = v; __syncthreads();
  for (int off=1; off<256; off<<=1){
    int x = (t>=off) ? sh[t-off] : 0;
    __syncthreads();
    sh[t] += x;
    __syncthreads();
  }
  if (t < nb) boff[t] = sh[t] - v;
}

__global__ void scan3_k(int* __restrict__ gscan, const int* __restrict__ boff,
                        int* __restrict__ bstart, int n){
  int i = blockIdx.x*256 + threadIdx.x;
  if (i < n){
    int v = gscan[i] + boff[i>>11];
    gscan[i] = v;
    if (i % NBLK == 0) bstart[i / NBLK] = v;
    if (i == 0) bstart[NB] = EDGES;
  }
}

// ---------------- phase C: LDS counting sort, then streamed coalesced write ----------------
// packed word: (dst & 63) << 17 | src

__global__ __launch_bounds__(256) void pC_k(const int* __restrict__ src,
    const int* __restrict__ dst, const int* __restrict__ gscan,
    u32* __restrict__ elist, int E){
  __shared__ int A[NB];        // hist -> excl -> delta
  __shared__ int B[NB];        // running local position (starts at excl)
  __shared__ int sp[256];      // scan partials
  __shared__ u32 pay[CHUNK];   // payload by local sorted index
  __shared__ u16 bkt[CHUNK];   // bucket by local sorted index
  int t = threadIdx.x, blk = blockIdx.x;
  for (int j = t; j < NB; j += 256) A[j] = 0;
  __syncthreads();
  int e0 = blk*CHUNK, e1 = e0 + CHUNK; if (e1 > E) e1 = E;
  int cnt = e1 - e0;
  for (int e = e0 + t; e < e1; e += 256) atomicAdd(&A[dst[e] >> BSH], 1);
  __syncthreads();
  // block-exclusive scan over A[0..NB): 7 elems/thread
  {
    int base = t*7;
    int cv[7]; int s = 0;
    #pragma unroll
    for (int j=0;j<7;++j){ int idx = base+j; cv[j] = (idx < NB) ? A[idx] : 0; s += cv[j]; }
    sp[t] = s; __syncthreads();
    for (int off=1; off<256; off<<=1){
      int x = (t>=off) ? sp[t-off] : 0;
      __syncthreads();
      sp[t] += x;
      __syncthreads();
    }
    int run = sp[t] - s;
    #pragma unroll
    for (int j=0;j<7;++j){
      int idx = base+j;
      if (idx < NB){ A[idx] = run; B[idx] = run; run += cv[j]; }
    }
  }
  __syncthreads();
  // delta[b] = global run start - local excl
  for (int j = t; j < NB; j += 256) A[j] = gscan[j*NBLK + blk] - A[j];
  __syncthreads();
  // placement into LDS sorted order
  for (int e = e0 + t; e < e1; e += 256){
    int d = dst[e];
    int b = d >> BSH;
    u32 w = ((u32)(d & (BNODES-1)) << 17) | (u32)src[e];
    int r = atomicAdd(&B[b], 1);
    pay[r] = w; bkt[r] = (u16)b;
  }
  __syncthreads();
  // streamed write: consecutive i -> consecutive global slots within runs
  for (int i = t; i < cnt; i += 256){
    int b = bkt[i];
    elist[i + A[b]] = pay[i];
  }
}

// ---------------- per-bucket counting sort (in place) + degrees ----------------
// NOTE: keeps the full packed word (dstloc<<17 | src) in elist.

__global__ __launch_bounds__(256) void csr_k(u32* __restrict__ elist,
    const int* __restrict__ bstart, int* __restrict__ offs, int* __restrict__ degs,
    float* __restrict__ invd, int M){
  __shared__ int hist[BNODES];
  __shared__ int pos[BNODES];
  __shared__ u32 buf[BCAP];
  __shared__ u32 buf2[BCAP];
  int b = blockIdx.x, t = threadIdx.x;
  if (b == 0 && t == 0) offs[M] = EDGES;     // sentinel for group ranges
  if (t < BNODES) hist[t] = 0;
  __syncthreads();
  int s0 = bstart[b];
  int cnt = bstart[b+1] - s0; if (cnt > BCAP) cnt = BCAP;
  u32* el = elist + s0;
  for (int e = t; e < cnt; e += 256){
    u32 w = el[e];
    buf[e] = w;
    atomicAdd(&hist[w>>17], 1);
  }
  __syncthreads();
  if (t < BNODES){                      // single-wave exclusive scan
    int v = hist[t];
    int s = v;
    for (int off = 1; off < BNODES; off <<= 1){
      int x = __shfl_up(s, off);
      if (t >= off) s += x;
    }
    int excl = s - v;
    pos[t] = excl;
    int node = b*BNODES + t;
    if (node < M){
      offs[node] = s0 + excl;
      degs[node] = v;
      invd[node] = 1.f / fmaxf((float)v, 1.f);
    }
  }
  __syncthreads();
  for (int e = t; e < cnt; e += 256){
    u32 w = buf[e];
    int p = atomicAdd(&pos[w>>17], 1);
    buf2[p] = w;                        // keep dstloc bits for MFMA aggregation
  }
  __syncthreads();
  for (int e = t; e < cnt; e += 256) el[e] = buf2[e];   // coalesced write-back
}

// ---------------- dtype conversion ----------------

__global__ void convf_k(const float* __restrict__ in, u16* __restrict__ o, int n4){
  int i = blockIdx.x*256 + threadIdx.x;
  if (i < n4){
    float4 x = ((const float4*)in)[i];
    ushort4 r;
    r.x = f2b(x.x); r.y = f2b(x.y); r.z = f2b(x.z); r.w = f2b(x.w);
    ((ushort4*)o)[i] = r;
  }
}

// W[K][N] row-major -> Wt[N][K] bf16
__global__ void convw_k(const float* __restrict__ W, u16* __restrict__ Wt, int Kd, int Nd){
  int i = blockIdx.x*256 + threadIdx.x;
  if (i < Kd*Nd){
    int k = i / Nd, nn = i - k*Nd;
    Wt[nn*Kd + k] = f2b(W[i]);
  }
}

// ---------------- GEMM: y[M x N] = h[M x 128] * W  (Wt is [N][128] bf16) ----------------

template<int NT>
__global__ __launch_bounds__(256) void gemm_k(const u16* __restrict__ h,
                                              const u16* __restrict__ Wt,
                                              u16* __restrict__ y, int M){
  const int K = FEATS;
  const int N = NT*16;
  int lane = threadIdx.x & 63;
  int wave = threadIdx.x >> 6;
  int m    = lane & 15;
  int quad = lane >> 4;
  int row0 = (blockIdx.x*4 + wave)*16;
  if (row0 >= M) return;
  int rowA = row0 + m; if (rowA > M-1) rowA = M-1;
  const u16* pa = h + (size_t)rowA*K + quad*8;

  f32x4 acc[NT];
  #pragma unroll
  for (int j=0;j<NT;++j) acc[j] = (f32x4){0.f,0.f,0.f,0.f};

  #pragma unroll
  for (int kk=0; kk<K; kk+=32){
    short8 a = *(const short8*)(pa + kk);
    #pragma unroll
    for (int j=0;j<NT;++j){
      short8 b = *(const short8*)(Wt + (size_t)(j*16 + m)*K + kk + quad*8);
      acc[j] = __builtin_amdgcn_mfma_f32_16x16x32_bf16(a, b, acc[j], 0, 0, 0);
    }
  }

  #pragma unroll
  for (int j=0;j<NT;++j){
    #pragma unroll
    for (int r=0;r<4;++r){
      int row = row0 + quad*4 + r;                  // C/D: row = quad*4 + reg
      if (row < M) y[(size_t)row*N + j*16 + m] = f2b(acc[j][r]);  // col = lane&15
    }
  }
}

// ---------------- MFMA aggregation (layers 0..2), 2-deep software pipeline ----
// One wave per 16 dst nodes. Per 32-edge k-step:
//   - gather 32 neighbor rows (256B each) into LDS as 4x16 subtiles
//   - indicator A-fragment (A[m][k] = 1 if edge k's dst-local == m)
//   - B-fragments via ds_read_b64_tr_b16 (per-lane addr base+(lane&15)*8)
//   - 8 MFMAs accumulate 16x128 output
// Pipeline: double-buffered LDS halves; edge-words prefetched 2 steps ahead
// via inline-asm global_load; counted waits keep next step's 8 gathers + 1
// word-load in flight across compute (never vmcnt(0) in the loop).
// Invariant at loop entry i: outstanding vmem = [L_{i+1}(1), G_i(8)].
//   wait vmcnt(8)  -> w_{i+1} arrived
//   issue L_{i+2}, G_{i+1}                  (outstanding 17)
//   wait vmcnt(9)  -> G_i done; tr_read buf[i&1]; MFMA
// Epilogue: exact f32  relu((1+eps)*y[v] + inv*sum + b), bf16 store.

#define TRRD(dstv, lit) asm volatile("ds_read_b64_tr_b16 %0, %1 offset:" lit \
                                     : "=v"(dstv) : "v"(trb_i))

__global__ __launch_bounds__(256) void aggM_k(const u16* __restrict__ y,
    const u32* __restrict__ el, const int* __restrict__ offs,
    const float* __restrict__ invd, const float* __restrict__ bias,
    const float* __restrict__ epsv, int ei, u16* __restrict__ hout){
  __shared__ __align__(128) u16 ybuf[4][2][4096];   // 16 KB per wave (2 halves)
  int lane = threadIdx.x & 63;
  int wave = threadIdx.x >> 6;
  int grp = blockIdx.x*4 + wave;
  if (grp >= NGRP) return;
  int v0 = grp << 4;
  int m    = lane & 15;
  int quad = lane >> 4;
  int li   = lane & 31;
  u32 tgt = (u32)(((grp & 3) << 4) + m);   // this lane's A-row as dst&63 value

  u16* lb0 = &ybuf[wave][0][0];
  typedef __attribute__((address_space(3))) u16 lds_u16;
  u32 lbaddr = (u32)(size_t)(lds_u16*)lb0;
  // tr-read base: subtile row-block quad*2 (bytes quad*2048), column slot m*8.
  u32 trb0 = lbaddr + (u32)(quad*2048) + (u32)(m*8);

  // gather addressing: inst i, lane l fetches row 4i+((l&7)>>1),
  // u16 cols (l>>3)*16 + (l&1)*8 .. +8  -> lands at subtiled LDS slot l*16B
  int rsel = (lane & 7) >> 1;
  int gcol = ((lane >> 3) << 4) + ((lane & 1) << 3);

  int e0 = offs[v0];
  int e1 = offs[v0 + 16];
  int nstep = (e1 - e0 + 31) >> 5;

  f32x4 acc[8];
  #pragma unroll
  for (int cb=0;cb<8;++cb) acc[cb] = (f32x4){0.f,0.f,0.f,0.f};

  // edge-word address for step st (clamped; validity handled by masking)
  auto elp = [&](int st)->const u32*{
    int idx = e0 + (st<<5) + li;
    if (idx > EDGES-1) idx = EDGES-1;
    return el + idx;
  };
  auto maskw = [&](u32 v, int st)->u32{
    int idx = e0 + (st<<5) + li;
    return (idx < e1) ? v : 0xFFFE0000u;   // pad: dstloc=0x7FFF, src=0
  };
  auto gathers = [&](u32 wm, u16* dstbuf){
    #pragma unroll
    for (int i=0;i<8;++i){
      u32 ws = (u32)__shfl((int)wm, 4*i + rsel);
      int srow = (int)(ws & 0x1FFFFu);
      gload16(y + ((size_t)srow << 7) + gcol, dstbuf + i*512);
    }
  };

  // ---- prologue: establish [L_1, G_0] outstanding ----
  u32 v0w;
  asm volatile("global_load_dword %0, %1, off" : "=v"(v0w) : "v"(elp(0)));
  asm volatile("s_waitcnt vmcnt(0)" : "+v"(v0w) :: "memory");
  u32 wcur = maskw(v0w, 0);
  u32 vnext;
  asm volatile("global_load_dword %0, %1, off" : "=v"(vnext) : "v"(elp(1)));
  gathers(wcur, lb0);

  for (int st = 0; st < nstep; ++st){
    // w_{st+1} arrived (8 gathers of step st still outstanding)
    asm volatile("s_waitcnt vmcnt(8)" : "+v"(vnext) :: "memory");
    u32 wn = maskw(vnext, st+1);
    u32 vfut;
    asm volatile("global_load_dword %0, %1, off" : "=v"(vfut) : "v"(elp(st+2)));
    gathers(wn, lb0 + (((st+1)&1) << 12));    // step st+1 -> other 8KB half

    // indicator A-fragment from wcur: lane holds A[m][quad*8+j], j=0..7
    union { u32 wv[4]; short8 s; } au;
    #pragma unroll
    for (int p=0;p<4;++p){
      u32 w0 = (u32)__shfl((int)wcur, quad*8 + 2*p);
      u32 w1 = (u32)__shfl((int)wcur, quad*8 + 2*p + 1);
      au.wv[p] = (((w0>>17) == tgt) ? 0x3F80u : 0u)
               | (((w1>>17) == tgt) ? 0x3F800000u : 0u);
    }

    // step st's gathers done; L_{st+2} + G_{st+1} (9) remain in flight
    asm volatile("s_waitcnt vmcnt(9)" ::: "memory");
    __builtin_amdgcn_sched_barrier(0);

    u32 trb_i = trb0 + (u32)((st&1) << 13);
    u64 t[16];
    TRRD(t[0],  "0");    TRRD(t[1],  "1024");
    TRRD(t[2],  "128");  TRRD(t[3],  "1152");
    TRRD(t[4],  "256");  TRRD(t[5],  "1280");
    TRRD(t[6],  "384");  TRRD(t[7],  "1408");
    TRRD(t[8],  "512");  TRRD(t[9],  "1536");
    TRRD(t[10], "640");  TRRD(t[11], "1664");
    TRRD(t[12], "768");  TRRD(t[13], "1792");
    TRRD(t[14], "896");  TRRD(t[15], "1920");
    asm volatile("s_waitcnt lgkmcnt(0)" ::: "memory");
    __builtin_amdgcn_sched_barrier(0);

    #pragma unroll
    for (int cb=0;cb<8;++cb){
      union { u64 d[2]; short8 s; } bu;
      bu.d[0] = t[2*cb]; bu.d[1] = t[2*cb+1];
      acc[cb] = __builtin_amdgcn_mfma_f32_16x16x32_bf16(au.s, bu.s, acc[cb], 0, 0, 0);
    }

    wcur = wn; vnext = vfut;
  }
  // drain leftover speculative loads before epilogue / exit
  asm volatile("s_waitcnt vmcnt(0)" ::: "memory");

  // epilogue: rows quad*4+r, cols cb*16+m
  float myinv = invd[v0 + m];
  float invr[4];
  #pragma unroll
  for (int r=0;r<4;++r) invr[r] = __shfl(myinv, quad*4 + r);
  float e1s = 1.f + epsv[ei];
  #pragma unroll
  for (int cb=0;cb<8;++cb){
    float bi = bias[cb*16 + m];
    #pragma unroll
    for (int r=0;r<4;++r){
      size_t off = (size_t)(v0 + quad*4 + r)*FEATS + cb*16 + m;
      float self = b2f(y[off]);
      float o = fmaxf(e1s*self + invr[r]*acc[cb][r] + bi, 0.f);
      hout[off] = f2b(o);
    }
  }
}

// ---------------- final 16-feat aggregation, f32 out, no relu ----------------
// 8 edges in parallel (sub = lane>>3), u32 loads (2 feats per lane).

__global__ __launch_bounds__(256) void aggF2_k(const u16* __restrict__ y,
    const u32* __restrict__ el, const int* __restrict__ offs,
    const int* __restrict__ degs, const float* __restrict__ invd,
    const float* __restrict__ bias, const float* __restrict__ epsv,
    float* __restrict__ out, int M){
  int lane = threadIdx.x & 63;
  int v = blockIdx.x*4 + (threadIdx.x >> 6);
  if (v >= M) return;
  int sub = lane >> 3;        // edge slot 0..7
  int f2  = lane & 7;         // feats 2f2, 2f2+1
  const u32* y2 = (const u32*)y;   // row stride = 8 u32
  int start = offs[v], deg = degs[v];
  float acc0 = 0.f, acc1 = 0.f;
  for (int e = sub; e < deg; e += 8){
    u32 s = el[start + e] & 0x1FFFFu;
    u32 p = y2[(size_t)s*8 + f2];
    acc0 += blo(p); acc1 += bhi(p);
  }
  acc0 += __shfl_xor(acc0, 8);  acc1 += __shfl_xor(acc1, 8);
  acc0 += __shfl_xor(acc0, 16); acc1 += __shfl_xor(acc1, 16);
  acc0 += __shfl_xor(acc0, 32); acc1 += __shfl_xor(acc1, 32);
  if (sub == 0){
    u32 pv = y2[(size_t)v*8 + f2];
    float2 bi = ((const float2*)bias)[f2];
    float e1s = 1.f + epsv[3];
    float inv = invd[v];
    out[(size_t)v*NCLS + 2*f2    ] = e1s*blo(pv) + inv*acc0 + bi.x;
    out[(size_t)v*NCLS + 2*f2 + 1] = e1s*bhi(pv) + inv*acc1 + bi.y;
  }
}

// ---------------- launch ----------------

extern "C" void kernel_launch(void* const* d_in, const int* in_sizes, int n_in,
                              void* d_out, int out_size, void* d_ws, size_t ws_size,
                              hipStream_t stream){
  const float* feats = (const float*)d_in[0];
  const int*   src   = (const int*)d_in[1];
  const int*   dst   = (const int*)d_in[2];
  const float* W0 = (const float*)d_in[3];  const float* b0 = (const float*)d_in[4];
  const float* W1 = (const float*)d_in[5];  const float* b1 = (const float*)d_in[6];
  const float* W2 = (const float*)d_in[7];  const float* b2 = (const float*)d_in[8];
  const float* W3 = (const float*)d_in[9];  const float* b3 = (const float*)d_in[10];
  const float* eps = (const float*)d_in[11];

  char* w = (char*)d_ws;
  auto alloc = [&](size_t bytes)->char*{
    char* p = w; w += (bytes + 255) & ~(size_t)255; return p;
  };
  int*  gh    = (int*)alloc(sizeof(int)*NHIST);
  int*  gscan = (int*)alloc(sizeof(int)*NHIST);
  int*  bsum  = (int*)alloc(sizeof(int)*256);
  int*  boff  = (int*)alloc(sizeof(int)*256);
  int*  bstart= (int*)alloc(sizeof(int)*(NB+1));
  int*  offs  = (int*)alloc(sizeof(int)*(NODES+1));
  int*  degs  = (int*)alloc(sizeof(int)*NODES);
  float* invd = (float*)alloc(sizeof(float)*NODES);
  u32*  elist = (u32*)alloc(sizeof(u32)*EDGES);
  u16*  hb    = (u16*)alloc(sizeof(u16)*(size_t)NODES*FEATS);
  u16*  yb    = (u16*)alloc(sizeof(u16)*(size_t)NODES*FEATS);
  u16*  Wt0   = (u16*)alloc(sizeof(u16)*128*128);
  u16*  Wt1   = (u16*)alloc(sizeof(u16)*128*128);
  u16*  Wt2   = (u16*)alloc(sizeof(u16)*128*128);
  u16*  Wt3   = (u16*)alloc(sizeof(u16)*16*128);

  // ---- deterministic 3-phase partition -> dense bucketed elist ----
  pA_k<<<NBLK, 256, 0, stream>>>(dst, gh, EDGES);
  int snb = (NHIST + 2047)/2048;                 // 150 <= 256
  scan1_k<<<snb, 256, 0, stream>>>(gh, gscan, bsum, NHIST);
  scan2_k<<<1, 256, 0, stream>>>(bsum, boff, snb);
  scan3_k<<<(NHIST+255)/256, 256, 0, stream>>>(gscan, boff, bstart, NHIST);
  pC_k<<<NBLK, 256, 0, stream>>>(src, dst, gscan, elist, EDGES);
  csr_k<<<NB, 256, 0, stream>>>(elist, bstart, offs, degs, invd, NODES);

  // ---- convert inputs to bf16 ----
  convf_k<<<((NODES*FEATS/4)+255)/256, 256, 0, stream>>>(feats, hb, NODES*FEATS/4);
  convw_k<<<(128*128+255)/256, 256, 0, stream>>>(W0, Wt0, 128, 128);
  convw_k<<<(128*128+255)/256, 256, 0, stream>>>(W1, Wt1, 128, 128);
  convw_k<<<(128*128+255)/256, 256, 0, stream>>>(W2, Wt2, 128, 128);
  convw_k<<<(128*16 +255)/256, 256, 0, stream>>>(W3, Wt3, 128, 16);

  int gblocks = (NODES + 63)/64;
  int mblocks = (NGRP + 3)/4;
  int ablocks = (NODES + 3)/4;

  // layers 0..2: y = h@W ; h = relu((1+eps)y + mean_agg(y) + b)
  gemm_k<8><<<gblocks, 256, 0, stream>>>(hb, Wt0, yb, NODES);
  aggM_k<<<mblocks, 256, 0, stream>>>(yb, elist, offs, invd, b0, eps, 0, hb);
  gemm_k<8><<<gblocks, 256, 0, stream>>>(hb, Wt1, yb, NODES);
  aggM_k<<<mblocks, 256, 0, stream>>>(yb, elist, offs, invd, b1, eps, 1, hb);
  gemm_k<8><<<gblocks, 256, 0, stream>>>(hb, Wt2, yb, NODES);
  aggM_k<<<mblocks, 256, 0, stream>>>(yb, elist, offs, invd, b2, eps, 2, hb);

  // layer 3: y = h@W3 (N=16); out = (1+eps)y + mean_agg(y) + b  (f32, no relu)
  gemm_k<1><<<gblocks, 256, 0, stream>>>(hb, Wt3, yb, NODES);
  aggF2_k<<<ablocks, 256, 0, stream>>>(yb, elist, offs, degs, invd, b3, eps, (float*)d_out, NODES);
}

// Round 5
// 456.942 us; speedup vs baseline: 1.1827x; 1.0924x over previous
//
#include <hip/hip_runtime.h>

#define NODES 100000
#define EDGES 1600000
#define FEATS 128
#define NCLS  16

// bucket = 64 consecutive dst nodes
#define BSH    6
#define BNODES 64
#define NB     ((NODES + BNODES - 1) / BNODES)   // 1563
#define CHUNK  8192
#define NBLK   ((EDGES + CHUNK - 1) / CHUNK)     // 196
#define NHIST  (NB * NBLK)                       // 306348
#define BCAP   2048                              // per-bucket LDS sort capacity
#define NGRP   ((NODES + 15) / 16)               // 6250 groups of 16 dst nodes

typedef unsigned int  u32;
typedef unsigned short u16;
typedef unsigned long long u64;
typedef __attribute__((ext_vector_type(8))) short short8;
typedef __attribute__((ext_vector_type(4))) float f32x4;

__device__ __forceinline__ float b2f(u16 v){ return __uint_as_float(((u32)v)<<16); }
__device__ __forceinline__ u16 f2b(float f){
  u32 u = __float_as_uint(f);
  u += 0x7fffu + ((u>>16)&1u);   // RNE
  return (u16)(u>>16);
}
__device__ __forceinline__ float blo(u32 p){ return __uint_as_float(p<<16); }
__device__ __forceinline__ float bhi(u32 p){ return __uint_as_float(p & 0xffff0000u); }

// global(16B) -> LDS, linear dest (wave-uniform base + lane*16), per-lane global src
__device__ __forceinline__ void gload16(const u16* g, u16* l){
  __builtin_amdgcn_global_load_lds(
      (const __attribute__((address_space(1))) u32*)g,
      (__attribute__((address_space(3))) u32*)l, 16, 0, 0);
}

// ---------------- phase A: per-chunk bucket histogram ----------------

__global__ __launch_bounds__(256) void pA_k(const int* __restrict__ dst,
                                            int* __restrict__ gh, int E){
  __shared__ int hist[NB];
  int t = threadIdx.x, blk = blockIdx.x;
  for (int j = t; j < NB; j += 256) hist[j] = 0;
  __syncthreads();
  int e0 = blk*CHUNK, e1 = e0 + CHUNK; if (e1 > E) e1 = E;
  for (int e = e0 + t; e < e1; e += 256) atomicAdd(&hist[dst[e] >> BSH], 1);
  __syncthreads();
  for (int j = t; j < NB; j += 256) gh[j*NBLK + blk] = hist[j];
}

// ---------------- phase B: exclusive scan of gh ----------------

__global__ __launch_bounds__(256) void scan1_k(const int* __restrict__ in, int* __restrict__ out,
                                               int* __restrict__ bsum, int n){
  __shared__ int sh[256];
  int t = threadIdx.x;
  int base = blockIdx.x*2048 + t*8;
  int v[8]; int s = 0;
  #pragma unroll
  for (int j=0;j<8;++j) v[j] = (base+j < n) ? in[base+j] : 0;
  #pragma unroll
  for (int j=0;j<8;++j){ int tmp = v[j]; v[j] = s; s += tmp; }
  sh[t] = s; __syncthreads();
  for (int off=1; off<256; off<<=1){
    int x = (t>=off) ? sh[t-off] : 0;
    __syncthreads();
    sh[t] += x;
    __syncthreads();
  }
  int excl = sh[t] - s;
  #pragma unroll
  for (int j=0;j<8;++j) if (base+j < n) out[base+j] = excl + v[j];
  if (t == 255) bsum[blockIdx.x] = sh[255];
}

// 256-entry block scan (nb <= 256)
__global__ __launch_bounds__(256) void scan2_k(const int* __restrict__ bsum,
                                               int* __restrict__ boff, int nb){
  __shared__ int sh[256];
  int t = threadIdx.x;
  int v = (t < nb) ? bsum[t] : 0;
  sh[t] = v; __syncthreads();
  for (int off=1; off<256; off<<=1){
    int x = (t>=off) ? sh[t-off] : 0;
    __syncthreads();
    sh[t] += x;
    __syncthreads();
  }
  if (t < nb) boff[t] = sh[t] - v;
}

__global__ void scan3_k(int* __restrict__ gscan, const int* __restrict__ boff,
                        int* __restrict__ bstart, int n){
  int i = blockIdx.x*256 + threadIdx.x;
  if (i < n){
    int v = gscan[i] + boff[i>>11];
    gscan[i] = v;
    if (i % NBLK == 0) bstart[i / NBLK] = v;
    if (i == 0) bstart[NB] = EDGES;
  }
}

// ---------------- phase C: LDS counting sort, then streamed coalesced write ----------------
// packed word: (dst & 63) << 17 | src

__global__ __launch_bounds__(256) void pC_k(const int* __restrict__ src,
    const int* __restrict__ dst, const int* __restrict__ gscan,
    u32* __restrict__ elist, int E){
  __shared__ int A[NB];        // hist -> excl -> delta
  __shared__ int B[NB];        // running local position (starts at excl)
  __shared__ int sp[256];      // scan partials
  __shared__ u32 pay[CHUNK];   // payload by local sorted index
  __shared__ u16 bkt[CHUNK];   // bucket by local sorted index
  int t = threadIdx.x, blk = blockIdx.x;
  for (int j = t; j < NB; j += 256) A[j] = 0;
  __syncthreads();
  int e0 = blk*CHUNK, e1 = e0 + CHUNK; if (e1 > E) e1 = E;
  int cnt = e1 - e0;
  for (int e = e0 + t; e < e1; e += 256) atomicAdd(&A[dst[e] >> BSH], 1);
  __syncthreads();
  // block-exclusive scan over A[0..NB): 7 elems/thread
  {
    int base = t*7;
    int cv[7]; int s = 0;
    #pragma unroll
    for (int j=0;j<7;++j){ int idx = base+j; cv[j] = (idx < NB) ? A[idx] : 0; s += cv[j]; }
    sp[t] = s; __syncthreads();
    for (int off=1; off<256; off<<=1){
      int x = (t>=off) ? sp[t-off] : 0;
      __syncthreads();
      sp[t] += x;
      __syncthreads();
    }
    int run = sp[t] - s;
    #pragma unroll
    for (int j=0;j<7;++j){
      int idx = base+j;
      if (idx < NB){ A[idx] = run; B[idx] = run; run += cv[j]; }
    }
  }
  __syncthreads();
  // delta[b] = global run start - local excl
  for (int j = t; j < NB; j += 256) A[j] = gscan[j*NBLK + blk] - A[j];
  __syncthreads();
  // placement into LDS sorted order
  for (int e = e0 + t; e < e1; e += 256){
    int d = dst[e];
    int b = d >> BSH;
    u32 w = ((u32)(d & (BNODES-1)) << 17) | (u32)src[e];
    int r = atomicAdd(&B[b], 1);
    pay[r] = w; bkt[r] = (u16)b;
  }
  __syncthreads();
  // streamed write: consecutive i -> consecutive global slots within runs
  for (int i = t; i < cnt; i += 256){
    int b = bkt[i];
    elist[i + A[b]] = pay[i];
  }
}

// ---------------- per-bucket counting sort (in place) + degrees ----------------
// NOTE: keeps the full packed word (dstloc<<17 | src) in elist.

__global__ __launch_bounds__(256) void csr_k(u32* __restrict__ elist,
    const int* __restrict__ bstart, int* __restrict__ offs, int* __restrict__ degs,
    float* __restrict__ invd, int M){
  __shared__ int hist[BNODES];
  __shared__ int pos[BNODES];
  __shared__ u32 buf[BCAP];
  __shared__ u32 buf2[BCAP];
  int b = blockIdx.x, t = threadIdx.x;
  if (b == 0 && t == 0) offs[M] = EDGES;     // sentinel for group ranges
  if (t < BNODES) hist[t] = 0;
  __syncthreads();
  int s0 = bstart[b];
  int cnt = bstart[b+1] - s0; if (cnt > BCAP) cnt = BCAP;
  u32* el = elist + s0;
  for (int e = t; e < cnt; e += 256){
    u32 w = el[e];
    buf[e] = w;
    atomicAdd(&hist[w>>17], 1);
  }
  __syncthreads();
  if (t < BNODES){                      // single-wave exclusive scan
    int v = hist[t];
    int s = v;
    for (int off = 1; off < BNODES; off <<= 1){
      int x = __shfl_up(s, off);
      if (t >= off) s += x;
    }
    int excl = s - v;
    pos[t] = excl;
    int node = b*BNODES + t;
    if (node < M){
      offs[node] = s0 + excl;
      degs[node] = v;
      invd[node] = 1.f / fmaxf((float)v, 1.f);
    }
  }
  __syncthreads();
  for (int e = t; e < cnt; e += 256){
    u32 w = buf[e];
    int p = atomicAdd(&pos[w>>17], 1);
    buf2[p] = w;                        // keep dstloc bits for MFMA aggregation
  }
  __syncthreads();
  for (int e = t; e < cnt; e += 256) el[e] = buf2[e];   // coalesced write-back
}

// ---------------- dtype conversion ----------------

__global__ void convf_k(const float* __restrict__ in, u16* __restrict__ o, int n4){
  int i = blockIdx.x*256 + threadIdx.x;
  if (i < n4){
    float4 x = ((const float4*)in)[i];
    ushort4 r;
    r.x = f2b(x.x); r.y = f2b(x.y); r.z = f2b(x.z); r.w = f2b(x.w);
    ((ushort4*)o)[i] = r;
  }
}

// W[K][N] row-major -> Wt[N][K] bf16
__global__ void convw_k(const float* __restrict__ W, u16* __restrict__ Wt, int Kd, int Nd){
  int i = blockIdx.x*256 + threadIdx.x;
  if (i < Kd*Nd){
    int k = i / Nd, nn = i - k*Nd;
    Wt[nn*Kd + k] = f2b(W[i]);
  }
}

// ---------------- GEMM (layer 0 only): y[M x N] = h[M x 128] * W  ----------------

template<int NT>
__global__ __launch_bounds__(256) void gemm_k(const u16* __restrict__ h,
                                              const u16* __restrict__ Wt,
                                              u16* __restrict__ y, int M){
  const int K = FEATS;
  const int N = NT*16;
  int lane = threadIdx.x & 63;
  int wave = threadIdx.x >> 6;
  int m    = lane & 15;
  int quad = lane >> 4;
  int row0 = (blockIdx.x*4 + wave)*16;
  if (row0 >= M) return;
  int rowA = row0 + m; if (rowA > M-1) rowA = M-1;
  const u16* pa = h + (size_t)rowA*K + quad*8;

  f32x4 acc[NT];
  #pragma unroll
  for (int j=0;j<NT;++j) acc[j] = (f32x4){0.f,0.f,0.f,0.f};

  #pragma unroll
  for (int kk=0; kk<K; kk+=32){
    short8 a = *(const short8*)(pa + kk);
    #pragma unroll
    for (int j=0;j<NT;++j){
      short8 b = *(const short8*)(Wt + (size_t)(j*16 + m)*K + kk + quad*8);
      acc[j] = __builtin_amdgcn_mfma_f32_16x16x32_bf16(a, b, acc[j], 0, 0, 0);
    }
  }

  #pragma unroll
  for (int j=0;j<NT;++j){
    #pragma unroll
    for (int r=0;r<4;++r){
      int row = row0 + quad*4 + r;                  // C/D: row = quad*4 + reg
      if (row < M) y[(size_t)row*N + j*16 + m] = f2b(acc[j][r]);  // col = lane&15
    }
  }
}

// ---------------- fused MFMA aggregation + next-layer GEMM (layers 0..2) ----
// One wave per 16 dst nodes. Gather loop identical to round-4 aggM (2-deep
// pipeline, counted vmcnt). After the accumulator epilogue produces
// h' = relu((1+eps)*y_self + inv*agg + b) in C-layout, the NEXT layer's GEMM
// y_next = h' @ Wn runs in the same wave:
//   - h' (bf16) written to a per-wave LDS scratch [16][136] (reuses the
//     now-idle gather buffer; stride 136 keeps ds_read_b128 16B-aligned and
//     conflicts at harmless 2-way)
//   - A-frags read back (lane m = node row m), B-frags from Wn (L2-hot),
//     4 k-step MFMAs per 16-col block; f2b store to yout.
// Numerically identical to the unfused gemm_k chain (same rounding points,
// same k order).

#define TRRD(dstv, lit) asm volatile("ds_read_b64_tr_b16 %0, %1 offset:" lit \
                                     : "=v"(dstv) : "v"(trb_i))

template<int NTO>
__global__ __launch_bounds__(256) void fagg_k(const u16* __restrict__ y,
    const u32* __restrict__ el, const int* __restrict__ offs,
    const float* __restrict__ invd, const float* __restrict__ bias,
    const float* __restrict__ epsv, int ei,
    const u16* __restrict__ Wn,     // next-layer weights, [NTO*16][128] bf16
    u16* __restrict__ yout){        // y_next, row stride NTO*16
  __shared__ __align__(128) u16 ybuf[4][2][4096];   // 16 KB per wave (2 halves)
  int lane = threadIdx.x & 63;
  int wave = threadIdx.x >> 6;
  int grp = blockIdx.x*4 + wave;
  if (grp >= NGRP) return;
  int v0 = grp << 4;
  int m    = lane & 15;
  int quad = lane >> 4;
  int li   = lane & 31;
  u32 tgt = (u32)(((grp & 3) << 4) + m);   // this lane's A-row as dst&63 value

  u16* lb0 = &ybuf[wave][0][0];
  typedef __attribute__((address_space(3))) u16 lds_u16;
  u32 lbaddr = (u32)(size_t)(lds_u16*)lb0;
  // tr-read base: subtile row-block quad*2 (bytes quad*2048), column slot m*8.
  u32 trb0 = lbaddr + (u32)(quad*2048) + (u32)(m*8);

  // gather addressing: inst i, lane l fetches row 4i+((l&7)>>1),
  // u16 cols (l>>3)*16 + (l&1)*8 .. +8  -> lands at subtiled LDS slot l*16B
  int rsel = (lane & 7) >> 1;
  int gcol = ((lane >> 3) << 4) + ((lane & 1) << 3);

  int e0 = offs[v0];
  int e1 = offs[v0 + 16];
  int nstep = (e1 - e0 + 31) >> 5;

  f32x4 acc[8];
  #pragma unroll
  for (int cb=0;cb<8;++cb) acc[cb] = (f32x4){0.f,0.f,0.f,0.f};

  // edge-word address for step st (clamped; validity handled by masking)
  auto elp = [&](int st)->const u32*{
    int idx = e0 + (st<<5) + li;
    if (idx > EDGES-1) idx = EDGES-1;
    return el + idx;
  };
  auto maskw = [&](u32 v, int st)->u32{
    int idx = e0 + (st<<5) + li;
    return (idx < e1) ? v : 0xFFFE0000u;   // pad: dstloc=0x7FFF, src=0
  };
  auto gathers = [&](u32 wm, u16* dstbuf){
    #pragma unroll
    for (int i=0;i<8;++i){
      u32 ws = (u32)__shfl((int)wm, 4*i + rsel);
      int srow = (int)(ws & 0x1FFFFu);
      gload16(y + ((size_t)srow << 7) + gcol, dstbuf + i*512);
    }
  };

  // ---- prologue: establish [L_1, G_0] outstanding ----
  u32 v0w;
  asm volatile("global_load_dword %0, %1, off" : "=v"(v0w) : "v"(elp(0)));
  asm volatile("s_waitcnt vmcnt(0)" : "+v"(v0w) :: "memory");
  u32 wcur = maskw(v0w, 0);
  u32 vnext;
  asm volatile("global_load_dword %0, %1, off" : "=v"(vnext) : "v"(elp(1)));
  gathers(wcur, lb0);

  for (int st = 0; st < nstep; ++st){
    // w_{st+1} arrived (8 gathers of step st still outstanding)
    asm volatile("s_waitcnt vmcnt(8)" : "+v"(vnext) :: "memory");
    u32 wn = maskw(vnext, st+1);
    u32 vfut;
    asm volatile("global_load_dword %0, %1, off" : "=v"(vfut) : "v"(elp(st+2)));
    gathers(wn, lb0 + (((st+1)&1) << 12));    // step st+1 -> other 8KB half

    // indicator A-fragment from wcur: lane holds A[m][quad*8+j], j=0..7
    union { u32 wv[4]; short8 s; } au;
    #pragma unroll
    for (int p=0;p<4;++p){
      u32 w0 = (u32)__shfl((int)wcur, quad*8 + 2*p);
      u32 w1 = (u32)__shfl((int)wcur, quad*8 + 2*p + 1);
      au.wv[p] = (((w0>>17) == tgt) ? 0x3F80u : 0u)
               | (((w1>>17) == tgt) ? 0x3F800000u : 0u);
    }

    // step st's gathers done; L_{st+2} + G_{st+1} (9) remain in flight
    asm volatile("s_waitcnt vmcnt(9)" ::: "memory");
    __builtin_amdgcn_sched_barrier(0);

    u32 trb_i = trb0 + (u32)((st&1) << 13);
    u64 t[16];
    TRRD(t[0],  "0");    TRRD(t[1],  "1024");
    TRRD(t[2],  "128");  TRRD(t[3],  "1152");
    TRRD(t[4],  "256");  TRRD(t[5],  "1280");
    TRRD(t[6],  "384");  TRRD(t[7],  "1408");
    TRRD(t[8],  "512");  TRRD(t[9],  "1536");
    TRRD(t[10], "640");  TRRD(t[11], "1664");
    TRRD(t[12], "768");  TRRD(t[13], "1792");
    TRRD(t[14], "896");  TRRD(t[15], "1920");
    asm volatile("s_waitcnt lgkmcnt(0)" ::: "memory");
    __builtin_amdgcn_sched_barrier(0);

    #pragma unroll
    for (int cb=0;cb<8;++cb){
      union { u64 d[2]; short8 s; } bu;
      bu.d[0] = t[2*cb]; bu.d[1] = t[2*cb+1];
      acc[cb] = __builtin_amdgcn_mfma_f32_16x16x32_bf16(au.s, bu.s, acc[cb], 0, 0, 0);
    }

    wcur = wn; vnext = vfut;
  }
  // drain leftover speculative loads before reusing the gather buffer
  asm volatile("s_waitcnt vmcnt(0)" ::: "memory");

  // ---- epilogue: h' = relu((1+eps)*y_self + inv*agg + b), into LDS scratch
  // h' C-layout: row quad*4+r, col cb*16+m. Scratch stride 136 u16 (272 B:
  // 16B-aligned rows for ds_read_b128, 2-way-conflict-free frag reads).
  float myinv = invd[v0 + m];
  float invr[4];
  #pragma unroll
  for (int r=0;r<4;++r) invr[r] = __shfl(myinv, quad*4 + r);
  float e1s = 1.f + epsv[ei];
  u16* zl = lb0;   // per-wave private; gather loop fully drained above
  #pragma unroll
  for (int cb=0;cb<8;++cb){
    float bi = bias[cb*16 + m];
    #pragma unroll
    for (int r=0;r<4;++r){
      size_t off = (size_t)(v0 + quad*4 + r)*FEATS + cb*16 + m;
      float self = b2f(y[off]);
      float h = fmaxf(e1s*self + invr[r]*acc[cb][r] + bi, 0.f);
      zl[(quad*4 + r)*136 + cb*16 + m] = f2b(h);
    }
  }

  // ---- fused next-layer GEMM: yout = h' @ Wn  (A = h' rows, B = Wn[n][k])
  short8 af[4];
  #pragma unroll
  for (int kb=0;kb<4;++kb)
    af[kb] = *(const short8*)(zl + m*136 + kb*32 + quad*8);

  #pragma unroll
  for (int nb=0;nb<NTO;++nb){
    f32x4 a2 = (f32x4){0.f,0.f,0.f,0.f};
    #pragma unroll
    for (int kb=0;kb<4;++kb){
      short8 bf = *(const short8*)(Wn + (size_t)(nb*16 + m)*FEATS + kb*32 + quad*8);
      a2 = __builtin_amdgcn_mfma_f32_16x16x32_bf16(af[kb], bf, a2, 0, 0, 0);
    }
    #pragma unroll
    for (int r=0;r<4;++r)
      yout[(size_t)(v0 + quad*4 + r)*(NTO*16) + nb*16 + m] = f2b(a2[r]);
  }
}

// ---------------- final 16-feat aggregation, f32 out, no relu ----------------
// 8 edges in parallel (sub = lane>>3), u32 loads (2 feats per lane).

__global__ __launch_bounds__(256) void aggF2_k(const u16* __restrict__ y,
    const u32* __restrict__ el, const int* __restrict__ offs,
    const int* __restrict__ degs, const float* __restrict__ invd,
    const float* __restrict__ bias, const float* __restrict__ epsv,
    float* __restrict__ out, int M){
  int lane = threadIdx.x & 63;
  int v = blockIdx.x*4 + (threadIdx.x >> 6);
  if (v >= M) return;
  int sub = lane >> 3;        // edge slot 0..7
  int f2  = lane & 7;         // feats 2f2, 2f2+1
  const u32* y2 = (const u32*)y;   // row stride = 8 u32
  int start = offs[v], deg = degs[v];
  float acc0 = 0.f, acc1 = 0.f;
  for (int e = sub; e < deg; e += 8){
    u32 s = el[start + e] & 0x1FFFFu;
    u32 p = y2[(size_t)s*8 + f2];
    acc0 += blo(p); acc1 += bhi(p);
  }
  acc0 += __shfl_xor(acc0, 8);  acc1 += __shfl_xor(acc1, 8);
  acc0 += __shfl_xor(acc0, 16); acc1 += __shfl_xor(acc1, 16);
  acc0 += __shfl_xor(acc0, 32); acc1 += __shfl_xor(acc1, 32);
  if (sub == 0){
    u32 pv = y2[(size_t)v*8 + f2];
    float2 bi = ((const float2*)bias)[f2];
    float e1s = 1.f + epsv[3];
    float inv = invd[v];
    out[(size_t)v*NCLS + 2*f2    ] = e1s*blo(pv) + inv*acc0 + bi.x;
    out[(size_t)v*NCLS + 2*f2 + 1] = e1s*bhi(pv) + inv*acc1 + bi.y;
  }
}

// ---------------- launch ----------------

extern "C" void kernel_launch(void* const* d_in, const int* in_sizes, int n_in,
                              void* d_out, int out_size, void* d_ws, size_t ws_size,
                              hipStream_t stream){
  const float* feats = (const float*)d_in[0];
  const int*   src   = (const int*)d_in[1];
  const int*   dst   = (const int*)d_in[2];
  const float* W0 = (const float*)d_in[3];  const float* b0 = (const float*)d_in[4];
  const float* W1 = (const float*)d_in[5];  const float* b1 = (const float*)d_in[6];
  const float* W2 = (const float*)d_in[7];  const float* b2 = (const float*)d_in[8];
  const float* W3 = (const float*)d_in[9];  const float* b3 = (const float*)d_in[10];
  const float* eps = (const float*)d_in[11];

  char* w = (char*)d_ws;
  auto alloc = [&](size_t bytes)->char*{
    char* p = w; w += (bytes + 255) & ~(size_t)255; return p;
  };
  int*  gh    = (int*)alloc(sizeof(int)*NHIST);
  int*  gscan = (int*)alloc(sizeof(int)*NHIST);
  int*  bsum  = (int*)alloc(sizeof(int)*256);
  int*  boff  = (int*)alloc(sizeof(int)*256);
  int*  bstart= (int*)alloc(sizeof(int)*(NB+1));
  int*  offs  = (int*)alloc(sizeof(int)*(NODES+1));
  int*  degs  = (int*)alloc(sizeof(int)*NODES);
  float* invd = (float*)alloc(sizeof(float)*NODES);
  u32*  elist = (u32*)alloc(sizeof(u32)*EDGES);
  u16*  hb    = (u16*)alloc(sizeof(u16)*(size_t)NODES*FEATS);
  u16*  yb    = (u16*)alloc(sizeof(u16)*(size_t)NODES*FEATS);
  u16*  Wt0   = (u16*)alloc(sizeof(u16)*128*128);
  u16*  Wt1   = (u16*)alloc(sizeof(u16)*128*128);
  u16*  Wt2   = (u16*)alloc(sizeof(u16)*128*128);
  u16*  Wt3   = (u16*)alloc(sizeof(u16)*16*128);

  // ---- deterministic 3-phase partition -> dense bucketed elist ----
  pA_k<<<NBLK, 256, 0, stream>>>(dst, gh, EDGES);
  int snb = (NHIST + 2047)/2048;                 // 150 <= 256
  scan1_k<<<snb, 256, 0, stream>>>(gh, gscan, bsum, NHIST);
  scan2_k<<<1, 256, 0, stream>>>(bsum, boff, snb);
  scan3_k<<<(NHIST+255)/256, 256, 0, stream>>>(gscan, boff, bstart, NHIST);
  pC_k<<<NBLK, 256, 0, stream>>>(src, dst, gscan, elist, EDGES);
  csr_k<<<NB, 256, 0, stream>>>(elist, bstart, offs, degs, invd, NODES);

  // ---- convert inputs to bf16 ----
  convf_k<<<((NODES*FEATS/4)+255)/256, 256, 0, stream>>>(feats, hb, NODES*FEATS/4);
  convw_k<<<(128*128+255)/256, 256, 0, stream>>>(W0, Wt0, 128, 128);
  convw_k<<<(128*128+255)/256, 256, 0, stream>>>(W1, Wt1, 128, 128);
  convw_k<<<(128*128+255)/256, 256, 0, stream>>>(W2, Wt2, 128, 128);
  convw_k<<<(128*16 +255)/256, 256, 0, stream>>>(W3, Wt3, 128, 16);

  int gblocks = (NODES + 63)/64;
  int mblocks = (NGRP + 3)/4;
  int ablocks = (NODES + 3)/4;

  // layer 0 GEMM: y0 = feats@W0
  gemm_k<8><<<gblocks, 256, 0, stream>>>(hb, Wt0, yb, NODES);
  // fused: h1 = relu((1+e0)y0 + mean(y0) + b0); y1 = h1@W1   (yb -> hb)
  fagg_k<8><<<mblocks, 256, 0, stream>>>(yb, elist, offs, invd, b0, eps, 0, Wt1, hb);
  // fused: h2 = relu((1+e1)y1 + mean(y1) + b1); y2 = h2@W2   (hb -> yb)
  fagg_k<8><<<mblocks, 256, 0, stream>>>(hb, elist, offs, invd, b1, eps, 1, Wt2, yb);
  // fused: h3 = relu((1+e2)y2 + mean(y2) + b2); y3 = h3@W3   (yb -> hb, 16 cols)
  fagg_k<1><<<mblocks, 256, 0, stream>>>(yb, elist, offs, invd, b2, eps, 2, Wt3, hb);
  // layer 3 epilogue: out = (1+e3)y3 + mean(y3) + b3  (f32, no relu)
  aggF2_k<<<ablocks, 256, 0, stream>>>(hb, elist, offs, degs, invd, b3, eps, (float*)d_out, NODES);
}